// Round 5
// baseline (103.217 us; speedup 1.0000x reference)
//
#include <hip/hip_runtime.h>

// HMM forward, B=8192, TMAX=2048, N=2 states, obs in {0,1}.
// One wave (64 lanes) per sequence. Straight-line structure:
//   - T load + first 8 obs-row loads issued immediately (unclamped, always
//     in-bounds: max index 1+7*64+63 = 512 <= 2048).
//   - remaining 24 row loads with word index CLAMPED to nwords-1 (repeat
//     loads of the same 256B line are L1 hits; no branches, full MLP).
//   - 32 unconditional __ballot's pack rows into 64-bit masks; lane L keeps
//     the 32-bit half covering its contiguous chunk [32L, 32L+32).
//   - fully-unrolled 32-step 2x2 matrix chain predicated on per-lane cnt
//     (garbage words belong to lanes with cnt==0 -> provably dead).
//   - ordered shuffle-tree combine; lane 0 applies alpha0 and writes out.
// __launch_bounds__(256,4): 128-VGPR budget so a[32] never spills, and grid
// (2048 blocks) = 2x resident capacity -> backfill smooths the T-imbalance
// tail that held OccupancyPercent at 51% in R1.
// NO LDS, NO __syncthreads (R2's LDS version failed post-timing validation).
#define TMAX_C 2048
#define ROWLEN (TMAX_C + 1)

__global__ __launch_bounds__(256, 4) void hmm_fwd_kernel(
    const int* __restrict__ combined,   // (B, TMAX+1): x[0..TMAX-1], T at [TMAX]
    const float* __restrict__ sp,       // (2,)  state prior logits
    const float* __restrict__ tr,       // (2,2) transition logits
    const float* __restrict__ emi,      // (2,2) emission logits
    float* __restrict__ out, int B)
{
    const int lane = threadIdx.x & 63;
    const int b = blockIdx.x * (blockDim.x >> 6) + (threadIdx.x >> 6);
    if (b >= B) return;

    const int* __restrict__ row = combined + (size_t)b * ROWLEN;

    // gating scalar, issued first
    const int T = row[TMAX_C];

    // ---- phase 1a: first 8 words unconditionally (overlap the T load) ----
    int a[32];
    #pragma unroll
    for (int w = 0; w < 8; ++w) {
        a[w] = row[1 + (w << 6) + lane];
    }

    const int steps = T - 1;                 // matrices applied at t = 1 .. T-1
    const int nwords = (steps + 63) >> 6;    // 64-obs words needed (0..32)
    const int wmax = max(nwords - 1, 0);

    // ---- phase 1b: remaining words, index clamped (branch-free) ----
    #pragma unroll
    for (int w = 8; w < 32; ++w) {
        const int wc = min(w, wmax);
        a[w] = row[1 + (wc << 6) + lane];
    }

    // ---- tiny softmaxes (overlap with outstanding loads) ----
    float p0 = __expf(sp[0]), p1 = __expf(sp[1]);
    { float s = p0 + p1; p0 /= s; p1 /= s; }
    float A00, A01, A10, A11;
    { float e0 = __expf(tr[0]), e1 = __expf(tr[1]); float s = e0 + e1; A00 = e0/s; A01 = e1/s; }
    { float e0 = __expf(tr[2]), e1 = __expf(tr[3]); float s = e0 + e1; A10 = e0/s; A11 = e1/s; }
    float em00, em01, em10, em11;   // em[state][obs]
    { float e0 = __expf(emi[0]), e1 = __expf(emi[1]); float s = e0 + e1; em00 = e0/s; em01 = e1/s; }
    { float e0 = __expf(emi[2]), e1 = __expf(emi[3]); float s = e0 + e1; em10 = e0/s; em11 = e1/s; }

    // M_o[i][j] = A[i][j] * em[j][o]   (row-vector convention)
    const float M0_00 = A00*em00, M0_01 = A01*em10, M0_10 = A10*em00, M0_11 = A11*em10;
    const float M1_00 = A00*em01, M1_01 = A01*em11, M1_10 = A10*em01, M1_11 = A11*em11;

    // ---- phase 2: 32 unconditional ballots; keep my word's half ----
    const int my_word = lane >> 1;           // lane's chunk = bits [32*lane, 32*lane+32)
    unsigned long long my_mask = 0ULL;
    #pragma unroll
    for (int w = 0; w < 32; ++w) {
        const unsigned long long m = __ballot(a[w] != 0);
        if (w == my_word) my_mask = m;
    }
    const unsigned int bits = (lane & 1) ? (unsigned int)(my_mask >> 32)
                                         : (unsigned int)my_mask;
    const int cnt = min(max(steps - (lane << 5), 0), 32);  // valid obs this lane

    // ---- phase 3: fully-unrolled 32-step 2x2 product chain ----
    float P00 = 1.f, P01 = 0.f, P10 = 0.f, P11 = 1.f;
    #pragma unroll
    for (int j = 0; j < 32; ++j) {
        const bool bit = (bits >> j) & 1u;
        const float m00 = bit ? M1_00 : M0_00;
        const float m01 = bit ? M1_01 : M0_01;
        const float m10 = bit ? M1_10 : M0_10;
        const float m11 = bit ? M1_11 : M0_11;
        const float n00 = P00*m00 + P01*m10;
        const float n01 = P00*m01 + P01*m11;
        const float n10 = P10*m00 + P11*m10;
        const float n11 = P10*m01 + P11*m11;
        const bool ok = j < cnt;
        P00 = ok ? n00 : P00;
        P01 = ok ? n01 : P01;
        P10 = ok ? n10 : P10;
        P11 = ok ? n11 : P11;
    }

    // ---- phase 4: ordered log-tree reduction across 64 lanes ----
    #pragma unroll
    for (int off = 1; off < 64; off <<= 1) {
        const float q00 = __shfl_down(P00, off);
        const float q01 = __shfl_down(P01, off);
        const float q10 = __shfl_down(P10, off);
        const float q11 = __shfl_down(P11, off);
        if (lane + off < 64) {
            const float n00 = P00*q00 + P01*q10;
            const float n01 = P00*q01 + P01*q11;
            const float n10 = P10*q00 + P11*q10;
            const float n11 = P10*q01 + P11*q11;
            P00 = n00; P01 = n01; P10 = n10; P11 = n11;
        }
    }

    if (lane == 0) {
        const int x0 = row[0];
        // alpha0[j] = em[j][x0] * priors[j]
        const float a0 = (x0 ? em01 : em00) * p0;
        const float a1 = (x0 ? em11 : em10) * p1;
        const float v0 = a0*P00 + a1*P10;
        const float v1 = a0*P01 + a1*P11;
        out[b] = v0 + v1;
    }
}

extern "C" void kernel_launch(void* const* d_in, const int* in_sizes, int n_in,
                              void* d_out, int out_size, void* d_ws, size_t ws_size,
                              hipStream_t stream) {
    const int*   combined = (const int*)d_in[0];
    const float* sp       = (const float*)d_in[1];
    const float* tr       = (const float*)d_in[2];
    const float* emi      = (const float*)d_in[3];
    float* out = (float*)d_out;

    const int B = out_size;                 // 8192 sequences, one output each
    const int waves_per_block = 4;          // 256 threads
    const int grid = (B + waves_per_block - 1) / waves_per_block;
    hmm_fwd_kernel<<<grid, 256, 0, stream>>>(combined, sp, tr, emi, out, B);
}

// Round 6
// 102.647 us; speedup vs baseline: 1.0056x; 1.0056x over previous
//
#include <hip/hip_runtime.h>

// HMM forward, B=8192, TMAX=2048, N=2 states, obs in {0,1}.
// One wave (64 lanes) per sequence.
//   Phase 1: coalesced 64-wide row loads, word-granularity wave-uniform
//            guards (avg T=1024 -> half the words skipped).
//   Phase 2: guarded __ballot packs each 64-obs row into a 64-bit mask;
//            lane L keeps the 32-bit half covering chunk [32L, 32L+32).
//   Phase 3: PAIR-LUT chain: 4 precomputed two-obs matrix products; 16
//            two-bit steps (12 cndmask select + 8 FMA + 4 commit) plus one
//            odd-tail single step. ~450 instrs vs 544 for the 1-bit chain.
//   Phase 4: ordered shuffle-tree combine; lane 0 applies alpha0, writes.
// NO LDS, NO __syncthreads (R2's LDS version failed post-timing validation).
#define TMAX_C 2048
#define ROWLEN (TMAX_C + 1)

__global__ __launch_bounds__(256, 4) void hmm_fwd_kernel(
    const int* __restrict__ combined,   // (B, TMAX+1): x[0..TMAX-1], T at [TMAX]
    const float* __restrict__ sp,       // (2,)  state prior logits
    const float* __restrict__ tr,       // (2,2) transition logits
    const float* __restrict__ emi,      // (2,2) emission logits
    float* __restrict__ out, int B)
{
    const int lane = threadIdx.x & 63;
    const int b = blockIdx.x * (blockDim.x >> 6) + (threadIdx.x >> 6);
    if (b >= B) return;

    const int* __restrict__ row = combined + (size_t)b * ROWLEN;
    const int T = row[TMAX_C];               // gates everything; issue first
    const int steps = T - 1;                 // matrices applied at t = 1 .. T-1
    const int nwords = (steps + 63) >> 6;    // 64-obs words needed (0..32)

    // ---- phase 1: guarded coalesced loads (wave-uniform branches) ----
    int a[32];
    #pragma unroll
    for (int w = 0; w < 32; ++w) {
        if (w < nwords) a[w] = row[1 + (w << 6) + lane];
    }

    // ---- tiny softmaxes with fast division (overlap outstanding loads) ----
    float p0 = __expf(sp[0]), p1 = __expf(sp[1]);
    { float s = __fdividef(1.f, p0 + p1); p0 *= s; p1 *= s; }
    float A00, A01, A10, A11;
    { float e0 = __expf(tr[0]), e1 = __expf(tr[1]); float s = __fdividef(1.f, e0 + e1); A00 = e0*s; A01 = e1*s; }
    { float e0 = __expf(tr[2]), e1 = __expf(tr[3]); float s = __fdividef(1.f, e0 + e1); A10 = e0*s; A11 = e1*s; }
    float em00, em01, em10, em11;   // em[state][obs]
    { float e0 = __expf(emi[0]), e1 = __expf(emi[1]); float s = __fdividef(1.f, e0 + e1); em00 = e0*s; em01 = e1*s; }
    { float e0 = __expf(emi[2]), e1 = __expf(emi[3]); float s = __fdividef(1.f, e0 + e1); em10 = e0*s; em11 = e1*s; }

    // M_o[i][j] = A[i][j] * em[j][o]   (row-vector convention)
    const float M0_00 = A00*em00, M0_01 = A01*em10, M0_10 = A10*em00, M0_11 = A11*em10;
    const float M1_00 = A00*em01, M1_01 = A01*em11, M1_10 = A10*em01, M1_11 = A11*em11;

    // Pair LUT: L[idx], idx = b0 + 2*b1, L = M_{b0} . M_{b1}
    const float L0_00 = M0_00*M0_00 + M0_01*M0_10, L0_01 = M0_00*M0_01 + M0_01*M0_11;
    const float L0_10 = M0_10*M0_00 + M0_11*M0_10, L0_11 = M0_10*M0_01 + M0_11*M0_11;
    const float L1_00 = M1_00*M0_00 + M1_01*M0_10, L1_01 = M1_00*M0_01 + M1_01*M0_11;
    const float L1_10 = M1_10*M0_00 + M1_11*M0_10, L1_11 = M1_10*M0_01 + M1_11*M0_11;
    const float L2_00 = M0_00*M1_00 + M0_01*M1_10, L2_01 = M0_00*M1_01 + M0_01*M1_11;
    const float L2_10 = M0_10*M1_00 + M0_11*M1_10, L2_11 = M0_10*M1_01 + M0_11*M1_11;
    const float L3_00 = M1_00*M1_00 + M1_01*M1_10, L3_01 = M1_00*M1_01 + M1_01*M1_11;
    const float L3_10 = M1_10*M1_00 + M1_11*M1_10, L3_11 = M1_10*M1_01 + M1_11*M1_11;

    // ---- phase 2: guarded ballots; keep my word's half ----
    const int my_word = lane >> 1;           // lane's chunk = bits [32*lane, 32*lane+32)
    unsigned long long my_mask = 0ULL;
    #pragma unroll
    for (int w = 0; w < 32; ++w) {
        if (w < nwords) {
            const unsigned long long m = __ballot(a[w] != 0);
            if (w == my_word) my_mask = m;
        }
    }
    const unsigned int bits = (lane & 1) ? (unsigned int)(my_mask >> 32)
                                         : (unsigned int)my_mask;
    const int cnt = min(max(steps - (lane << 5), 0), 32);  // valid obs this lane

    // ---- phase 3: pair-LUT chain, 16 two-bit steps + odd tail ----
    float P00 = 1.f, P01 = 0.f, P10 = 0.f, P11 = 1.f;
    #pragma unroll
    for (int j = 0; j < 16; ++j) {
        const bool b0 = (bits >> (2*j)) & 1u;
        const bool b1 = (bits >> (2*j + 1)) & 1u;
        // select L[b0 + 2*b1]
        const float t00a = b0 ? L1_00 : L0_00, t00b = b0 ? L3_00 : L2_00;
        const float t01a = b0 ? L1_01 : L0_01, t01b = b0 ? L3_01 : L2_01;
        const float t10a = b0 ? L1_10 : L0_10, t10b = b0 ? L3_10 : L2_10;
        const float t11a = b0 ? L1_11 : L0_11, t11b = b0 ? L3_11 : L2_11;
        const float q00 = b1 ? t00b : t00a;
        const float q01 = b1 ? t01b : t01a;
        const float q10 = b1 ? t10b : t10a;
        const float q11 = b1 ? t11b : t11a;
        const float n00 = P00*q00 + P01*q10;
        const float n01 = P00*q01 + P01*q11;
        const float n10 = P10*q00 + P11*q10;
        const float n11 = P10*q01 + P11*q11;
        const bool ok = (2*j + 2) <= cnt;    // commit whole pairs only
        P00 = ok ? n00 : P00;
        P01 = ok ? n01 : P01;
        P10 = ok ? n10 : P10;
        P11 = ok ? n11 : P11;
    }
    {   // odd tail: one more single-obs step on lanes with odd cnt
        const bool odd = (cnt & 1);
        const unsigned int lastbit = (bits >> (cnt > 0 ? cnt - 1 : 0)) & 1u;
        const float m00 = lastbit ? M1_00 : M0_00;
        const float m01 = lastbit ? M1_01 : M0_01;
        const float m10 = lastbit ? M1_10 : M0_10;
        const float m11 = lastbit ? M1_11 : M0_11;
        const float n00 = P00*m00 + P01*m10;
        const float n01 = P00*m01 + P01*m11;
        const float n10 = P10*m00 + P11*m10;
        const float n11 = P10*m01 + P11*m11;
        P00 = odd ? n00 : P00;
        P01 = odd ? n01 : P01;
        P10 = odd ? n10 : P10;
        P11 = odd ? n11 : P11;
    }

    // ---- phase 4: ordered log-tree reduction across 64 lanes ----
    #pragma unroll
    for (int off = 1; off < 64; off <<= 1) {
        const float q00 = __shfl_down(P00, off);
        const float q01 = __shfl_down(P01, off);
        const float q10 = __shfl_down(P10, off);
        const float q11 = __shfl_down(P11, off);
        if (lane + off < 64) {
            const float n00 = P00*q00 + P01*q10;
            const float n01 = P00*q01 + P01*q11;
            const float n10 = P10*q00 + P11*q10;
            const float n11 = P10*q01 + P11*q11;
            P00 = n00; P01 = n01; P10 = n10; P11 = n11;
        }
    }

    if (lane == 0) {
        const int x0 = row[0];
        // alpha0[j] = em[j][x0] * priors[j]
        const float a0 = (x0 ? em01 : em00) * p0;
        const float a1 = (x0 ? em11 : em10) * p1;
        const float v0 = a0*P00 + a1*P10;
        const float v1 = a0*P01 + a1*P11;
        out[b] = v0 + v1;
    }
}

extern "C" void kernel_launch(void* const* d_in, const int* in_sizes, int n_in,
                              void* d_out, int out_size, void* d_ws, size_t ws_size,
                              hipStream_t stream) {
    const int*   combined = (const int*)d_in[0];
    const float* sp       = (const float*)d_in[1];
    const float* tr       = (const float*)d_in[2];
    const float* emi      = (const float*)d_in[3];
    float* out = (float*)d_out;

    const int B = out_size;                 // 8192 sequences, one output each
    const int waves_per_block = 4;          // 256 threads
    const int grid = (B + waves_per_block - 1) / waves_per_block;
    hmm_fwd_kernel<<<grid, 256, 0, stream>>>(combined, sp, tr, emi, out, B);
}